// Round 17
// baseline (176.707 us; speedup 1.0000x reference)
//
#include <hip/hip_runtime.h>
#include <hip/hip_cooperative_groups.h>
#include <math.h>

#define DEV __device__ __forceinline__

namespace cg = cooperative_groups;

typedef short s16x8 __attribute__((ext_vector_type(8)));
typedef float f32x4 __attribute__((ext_vector_type(4)));

// ---- ws dword layout ----
// [0..3]: reduction slots (bit patterns of non-negative floats)
static constexpr int W1S = 16;   // 64 per-out-row weight scales
static constexpr int W2S = 80;   // 32
static constexpr int W3S = 112;  // 32
static constexpr int W4S = 144;  // 5
static constexpr int F0  = 256;  // 18 A-fragments (weights), each 64 lanes x int4
// frag ids: 0..3 = A1[nt] | 4..11 = A2[mt*4+c] | 12..15 = A3[mt*2+c] | 16..17 = A4[c]

DEV float qbias(float b, float bs) {
    float q = rintf(b / bs);
    return fminf(fmaxf(q, -2.147483648e9f), 2.147483648e9f);
}

DEV unsigned short bf16b(float f) {  // values used are exact in bf16 -> truncate
    return (unsigned short)(__float_as_uint(f) >> 16);
}

DEV void reduceAndAtomicMax(float v, unsigned int* slot) {
    #pragma unroll
    for (int off = 32; off; off >>= 1) v = fmaxf(v, __shfl_xor(v, off));
    __shared__ float sm[16];
    const int wid = threadIdx.x >> 6;
    if ((threadIdx.x & 63) == 0) sm[wid] = v;
    __syncthreads();
    if (threadIdx.x == 0) {
        const int nw = blockDim.x >> 6;
        float m = sm[0];
        for (int i = 1; i < nw; i++) m = fmaxf(m, sm[i]);
        atomicMax(slot, __float_as_uint(m)); // non-negative: bit order == value order
    }
    __syncthreads();
}

DEV float ldscale(const unsigned int* p) {  // agent-scope coherent scale load
    unsigned u = __hip_atomic_load(p, __ATOMIC_RELAXED, __HIP_MEMORY_SCOPE_AGENT);
    return fmaxf(__uint_as_float(u) * (1.f / 32767.f), 1e-8f);
}

// ---- setup: quantize weights, emit k-permuted A-fragments (weights as MFMA A) ----
__global__ __launch_bounds__(256) void k_quantw(const float* __restrict__ W1,
                                                const float* __restrict__ W2,
                                                const float* __restrict__ W3,
                                                const float* __restrict__ W4,
                                                float* __restrict__ wsf) {
    __shared__ int wq1[64 * 16], wq2[32 * 64], wq3[32 * 32], wq4[5 * 32];
    int* wsi = (int*)wsf;
    const int t = threadIdx.x;
    if (t < 4) ((unsigned int*)wsf)[t] = 0u;

    const float* W = nullptr; int row = -1, cols = 0; int* dq = nullptr; float* dsc = nullptr;
    if (t < 64)       { W = W1; row = t;       cols = 16; dq = wq1 + row * 16; dsc = wsf + W1S + row; }
    else if (t < 96)  { W = W2; row = t - 64;  cols = 64; dq = wq2 + row * 64; dsc = wsf + W2S + row; }
    else if (t < 128) { W = W3; row = t - 96;  cols = 32; dq = wq3 + row * 32; dsc = wsf + W3S + row; }
    else if (t < 133) { W = W4; row = t - 128; cols = 32; dq = wq4 + row * 32; dsc = wsf + W4S + row; }
    if (row >= 0) {
        const float* src = W + row * cols;
        float m = 0.f;
        for (int i = 0; i < cols; i++) m = fmaxf(m, fabsf(src[i]));
        float s = fmaxf(m * (1.0f / 127.0f), 1e-8f);
        *dsc = s;
        for (int i = 0; i < cols; i++) {
            float q = fminf(fmaxf(rintf(src[i] / s), -128.f), 127.f);
            dq[i] = (int)q;
        }
    }
    __syncthreads();

    // A-fragment: lane l holds A[row = l&15][k = (l>>4)*8 + e].
    //  L1: k=8*grp+e -> feature (grp&1)*8 + e           (grp>>1 = hi/lo)
    //  L2/L3/L4 chunk c: k=8*grp+e -> feature 16c + 4*grp + (e&3)  (e>>2 = hi/lo)
    for (int sIdx = t; sIdx < 18 * 64; sIdx += 256) {
        const int f = sIdx >> 6, l = sIdx & 63;
        const int grp = l >> 4, li = l & 15;
        int dw[4];
        #pragma unroll
        for (int d = 0; d < 4; d++) {
            unsigned int hv[2];
            #pragma unroll
            for (int h = 0; h < 2; h++) {
                const int e = 2 * d + h;
                int wv;
                if (f < 4) {
                    wv = wq1[(f * 16 + li) * 16 + (grp & 1) * 8 + e];
                } else if (f < 12) {
                    int mt = (f - 4) >> 2, c = (f - 4) & 3;
                    wv = wq2[(mt * 16 + li) * 64 + 16 * c + 4 * grp + (e & 3)];
                } else if (f < 16) {
                    int mt = (f - 12) >> 1, c = (f - 12) & 1;
                    wv = wq3[(mt * 16 + li) * 32 + 16 * c + 4 * grp + (e & 3)];
                } else {
                    int c = f - 16;
                    wv = (li < 5) ? wq4[li * 32 + 16 * c + 4 * grp + (e & 3)] : 0;
                }
                hv[h] = bf16b((float)wv);
            }
            dw[d] = (int)(hv[0] | (hv[1] << 16));
        }
        ((int4*)(wsi + F0))[f * 64 + l] = make_int4(dw[0], dw[1], dw[2], dw[3]);
    }
}

// pack bf16 bits of two low16-zero floats into one dword: {b0>>16, b1>>16}
DEV int packhi(float q0, float q1) {
    return (int)__builtin_amdgcn_perm(__float_as_uint(q1), __float_as_uint(q0), 0x07060302u);
}

// quant(+relu) + truncation split; upper clamp provably never binds (r15-validated)
DEV void qsplit2(float a0, float a1, float2 c0, float2 c1, int& hw, int& lw) {
    float t0 = fmaf(a0, c0.x, c0.y);
    float t1 = fmaf(a1, c1.x, c1.y);
    float q0 = fmaxf(rintf(t0), 0.f);
    float q1 = fmaxf(rintf(t1), 0.f);
    float h0 = __uint_as_float(__float_as_uint(q0) & 0xFFFF0000u); // top 8 sig bits
    float h1 = __uint_as_float(__float_as_uint(q1) & 0xFFFF0000u);
    hw = packhi(h0, h1);
    lw = packhi(q0 - h0, q1 - h1);  // residual <= 7 sig bits, bf16-exact
}

DEV s16x8 mkfrag(f32x4 acc, const float2* cq) {
    int h01, h23, l01, l23;
    qsplit2(acc[0], acc[1], cq[0], cq[1], h01, l01);
    qsplit2(acc[2], acc[3], cq[2], cq[3], h23, l23);
    return __builtin_bit_cast(s16x8, make_int4(h01, h23, l01, l23));
}

DEV float qxsel(float v, float inv0, bool hi) {
    float q = rintf(v * inv0);
    float h = __uint_as_float(__float_as_uint(q) & 0xFFFF0000u);
    return hi ? h : (q - h);
}

// ---- per-phase compute, grid-stride over 16-row tiles ----
template <int STAGE>
DEV void phase_body(const float* __restrict__ x,
                    const float* __restrict__ b1, const float* __restrict__ b2,
                    const float* __restrict__ b3, const float* __restrict__ b4,
                    const float* __restrict__ wsf, unsigned int* __restrict__ slots,
                    float* __restrict__ out, int nTiles, int waveId, int totalWaves) {
    __shared__ float2 QA[64], QB[32], QC[32], QD[16];
    const int t = threadIdx.x;
    const int l = t & 63;
    const int grp = l >> 4, li = l & 15;

    const float s0 = ldscale(slots + 0);
    float s1 = 1.f, s2 = 1.f, s3 = 1.f;
    if (STAGE >= 2) s1 = ldscale(slots + 1);
    if (STAGE >= 3) s2 = ldscale(slots + 2);
    if (STAGE >= 4) s3 = ldscale(slots + 3);
    const float inv0 = 1.f / s0;
    const float inv1 = (STAGE >= 2) ? 1.f / s1 : 0.f;
    const float inv2 = (STAGE >= 3) ? 1.f / s2 : 0.f;
    const float inv3 = (STAGE >= 4) ? 1.f / s3 : 0.f;

    if (t < 64) {
        float bs = wsf[W1S + t] * s0; float bi = qbias(b1[t], bs) * bs;
        QA[t] = (STAGE == 1) ? make_float2(bs, bi) : make_float2(bs * inv1, bi * inv1);
    }
    if (STAGE >= 2 && t >= 64 && t < 96) {
        int i = t - 64;
        float bs = wsf[W2S + i] * s1; float bi = qbias(b2[i], bs) * bs;
        QB[i] = (STAGE == 2) ? make_float2(bs, bi) : make_float2(bs * inv2, bi * inv2);
    }
    if (STAGE >= 3 && t >= 96 && t < 128) {
        int i = t - 96;
        float bs = wsf[W3S + i] * s2; float bi = qbias(b3[i], bs) * bs;
        QC[i] = (STAGE == 3) ? make_float2(bs, bi) : make_float2(bs * inv3, bi * inv3);
    }
    if (STAGE >= 4 && t >= 128 && t < 144) {
        int i = t - 128;
        if (i < 5) { float bs = wsf[W4S + i] * s3; QD[i] = make_float2(bs, qbias(b4[i], bs) * bs); }
        else QD[i] = make_float2(0.f, 0.f);
    }
    __syncthreads();

    const int4* fr = (const int4*)((const int*)wsf + F0);
    s16x8 A1[4], A2[2][4], A3[2][2], A4[2];
    #pragma unroll
    for (int nt = 0; nt < 4; nt++) A1[nt] = __builtin_bit_cast(s16x8, fr[nt * 64 + l]);
    if (STAGE >= 2)
        #pragma unroll
        for (int mt = 0; mt < 2; mt++)
            #pragma unroll
            for (int c = 0; c < 4; c++) A2[mt][c] = __builtin_bit_cast(s16x8, fr[(4 + mt * 4 + c) * 64 + l]);
    if (STAGE >= 3)
        #pragma unroll
        for (int mt = 0; mt < 2; mt++)
            #pragma unroll
            for (int c = 0; c < 2; c++) A3[mt][c] = __builtin_bit_cast(s16x8, fr[(12 + mt * 2 + c) * 64 + l]);
    if (STAGE >= 4) {
        A4[0] = __builtin_bit_cast(s16x8, fr[16 * 64 + l]);
        A4[1] = __builtin_bit_cast(s16x8, fr[17 * 64 + l]);
    }

    float2 cq1[4][4], cq2[2][4], cq3[2][4], e4[4];
    if (STAGE >= 2)
        #pragma unroll
        for (int nt = 0; nt < 4; nt++)
            #pragma unroll
            for (int r = 0; r < 4; r++) cq1[nt][r] = QA[16 * nt + 4 * grp + r];
    if (STAGE >= 3)
        #pragma unroll
        for (int mt = 0; mt < 2; mt++)
            #pragma unroll
            for (int r = 0; r < 4; r++) cq2[mt][r] = QB[16 * mt + 4 * grp + r];
    if (STAGE >= 4) {
        #pragma unroll
        for (int mt = 0; mt < 2; mt++)
            #pragma unroll
            for (int r = 0; r < 4; r++) cq3[mt][r] = QC[16 * mt + 4 * grp + r];
        #pragma unroll
        for (int r = 0; r < 4; r++) e4[r] = QD[4 * grp + r];
    }

    float ma1[4][4], ma2[2][4], ma3[2][4];
    if (STAGE == 1)
        #pragma unroll
        for (int nt = 0; nt < 4; nt++)
            #pragma unroll
            for (int r = 0; r < 4; r++) ma1[nt][r] = -3.402823466e38f;
    if (STAGE == 2)
        #pragma unroll
        for (int mt = 0; mt < 2; mt++)
            #pragma unroll
            for (int r = 0; r < 4; r++) ma2[mt][r] = -3.402823466e38f;
    if (STAGE == 3)
        #pragma unroll
        for (int mt = 0; mt < 2; mt++)
            #pragma unroll
            for (int r = 0; r < 4; r++) ma3[mt][r] = -3.402823466e38f;

    const bool hiLane = (grp < 2);

    float4 px0 = {0.f, 0.f, 0.f, 0.f}, px1 = {0.f, 0.f, 0.f, 0.f};
    int tile = waveId;
    if (tile < nTiles) {
        const float4* xr = (const float4*)(x + ((size_t)tile * 16 + li) * 16 + (grp & 1) * 8);
        px0 = xr[0]; px1 = xr[1];
    }
    for (; tile < nTiles; tile += totalWaves) {
        float4 v0 = px0, v1 = px1;
        const int nxt = tile + totalWaves;
        if (nxt < nTiles) {
            const float4* xr = (const float4*)(x + ((size_t)nxt * 16 + li) * 16 + (grp & 1) * 8);
            px0 = xr[0]; px1 = xr[1];
        }
        const size_t row0 = (size_t)tile * 16;

        s16x8 b1v;
        {
            float p0 = qxsel(v0.x, inv0, hiLane), p1 = qxsel(v0.y, inv0, hiLane);
            float p2 = qxsel(v0.z, inv0, hiLane), p3 = qxsel(v0.w, inv0, hiLane);
            float p4 = qxsel(v1.x, inv0, hiLane), p5 = qxsel(v1.y, inv0, hiLane);
            float p6 = qxsel(v1.z, inv0, hiLane), p7 = qxsel(v1.w, inv0, hiLane);
            b1v = __builtin_bit_cast(s16x8,
                make_int4(packhi(p0, p1), packhi(p2, p3), packhi(p4, p5), packhi(p6, p7)));
        }

        s16x8 B2f[4];
        #pragma unroll
        for (int nt = 0; nt < 4; nt++) {
            f32x4 acc = {0.f, 0.f, 0.f, 0.f};
            acc = __builtin_amdgcn_mfma_f32_16x16x32_bf16(A1[nt], b1v, acc, 0, 0, 0);
            if constexpr (STAGE == 1) {
                #pragma unroll
                for (int r = 0; r < 4; r++) ma1[nt][r] = fmaxf(ma1[nt][r], acc[r]);
            } else {
                B2f[nt] = mkfrag(acc, cq1[nt]);
            }
        }
        if constexpr (STAGE == 1) continue;

        f32x4 acc2[2] = {{0.f, 0.f, 0.f, 0.f}, {0.f, 0.f, 0.f, 0.f}};
        #pragma unroll
        for (int c = 0; c < 4; c++) {
            acc2[0] = __builtin_amdgcn_mfma_f32_16x16x32_bf16(A2[0][c], B2f[c], acc2[0], 0, 0, 0);
            acc2[1] = __builtin_amdgcn_mfma_f32_16x16x32_bf16(A2[1][c], B2f[c], acc2[1], 0, 0, 0);
        }
        if constexpr (STAGE == 2) {
            #pragma unroll
            for (int mt = 0; mt < 2; mt++)
                #pragma unroll
                for (int r = 0; r < 4; r++) ma2[mt][r] = fmaxf(ma2[mt][r], acc2[mt][r]);
            continue;
        }

        if constexpr (STAGE >= 3) {
            s16x8 B3f[2];
            #pragma unroll
            for (int c = 0; c < 2; c++) B3f[c] = mkfrag(acc2[c], cq2[c]);

            f32x4 acc3[2] = {{0.f, 0.f, 0.f, 0.f}, {0.f, 0.f, 0.f, 0.f}};
            #pragma unroll
            for (int c = 0; c < 2; c++) {
                acc3[0] = __builtin_amdgcn_mfma_f32_16x16x32_bf16(A3[0][c], B3f[c], acc3[0], 0, 0, 0);
                acc3[1] = __builtin_amdgcn_mfma_f32_16x16x32_bf16(A3[1][c], B3f[c], acc3[1], 0, 0, 0);
            }
            if constexpr (STAGE == 3) {
                #pragma unroll
                for (int mt = 0; mt < 2; mt++)
                    #pragma unroll
                    for (int r = 0; r < 4; r++) ma3[mt][r] = fmaxf(ma3[mt][r], acc3[mt][r]);
                continue;
            }

            if constexpr (STAGE == 4) {
                s16x8 B4f[2];
                #pragma unroll
                for (int c = 0; c < 2; c++) B4f[c] = mkfrag(acc3[c], cq3[c]);

                f32x4 acc4 = {0.f, 0.f, 0.f, 0.f};
                acc4 = __builtin_amdgcn_mfma_f32_16x16x32_bf16(A4[0], B4f[0], acc4, 0, 0, 0);
                acc4 = __builtin_amdgcn_mfma_f32_16x16x32_bf16(A4[1], B4f[1], acc4, 0, 0, 0);

                float lg0 = fmaf(acc4[0], e4[0].x, e4[0].y);
                float lg1 = fmaf(acc4[1], e4[1].x, e4[1].y);
                float lg2 = fmaf(acc4[2], e4[2].x, e4[2].y);
                float lg3 = fmaf(acc4[3], e4[3].x, e4[3].y);
                float lg4 = __shfl(lg0, li + 16);  // grp1 reg0 = feature 4

                if (l < 16) {
                    float m = fmaxf(fmaxf(fmaxf(lg0, lg1), fmaxf(lg2, lg3)), lg4);
                    float e0 = __expf(lg0 - m), e1 = __expf(lg1 - m), e2 = __expf(lg2 - m),
                          e3 = __expf(lg3 - m), ee4 = __expf(lg4 - m);
                    float r = 1.f / (e0 + e1 + e2 + e3 + ee4);
                    float* dst = out + (row0 + l) * 5;
                    dst[0] = e0 * r; dst[1] = e1 * r; dst[2] = e2 * r; dst[3] = e3 * r; dst[4] = ee4 * r;
                }
            }
        }
    }

    if (STAGE == 1) {
        float vmax = 0.f;
        #pragma unroll
        for (int nt = 0; nt < 4; nt++)
            #pragma unroll
            for (int r = 0; r < 4; r++) {
                float2 c = QA[16 * nt + 4 * grp + r];
                vmax = fmaxf(vmax, fmaf(ma1[nt][r], c.x, c.y));
            }
        reduceAndAtomicMax(vmax, slots + 1);
    } else if (STAGE == 2) {
        float vmax = 0.f;
        #pragma unroll
        for (int mt = 0; mt < 2; mt++)
            #pragma unroll
            for (int r = 0; r < 4; r++) {
                float2 c = QB[16 * mt + 4 * grp + r];
                vmax = fmaxf(vmax, fmaf(ma2[mt][r], c.x, c.y));
            }
        reduceAndAtomicMax(vmax, slots + 2);
    } else if (STAGE == 3) {
        float vmax = 0.f;
        #pragma unroll
        for (int mt = 0; mt < 2; mt++)
            #pragma unroll
            for (int r = 0; r < 4; r++) {
                float2 c = QC[16 * mt + 4 * grp + r];
                vmax = fmaxf(vmax, fmaf(ma3[mt][r], c.x, c.y));
            }
        reduceAndAtomicMax(vmax, slots + 3);
    }
}

// ---- fused cooperative kernel: (512,2) = 256-reg budget (r13/r16-proven spill-free) ----
__global__ __launch_bounds__(512, 2) void k_fused(const float* __restrict__ x,
                                                  const float* __restrict__ b1,
                                                  const float* __restrict__ b2,
                                                  const float* __restrict__ b3,
                                                  const float* __restrict__ b4,
                                                  const float* __restrict__ wsf,
                                                  unsigned int* __restrict__ slots,
                                                  float* __restrict__ out,
                                                  int nTiles, int n4) {
    cg::grid_group gg = cg::this_grid();
    const int t = threadIdx.x;
    const int waveId = blockIdx.x * 8 + (t >> 6);
    const int totalWaves = gridDim.x * 8;

    // phase 0: max|x|
    {
        float m = 0.f;
        const float4* xv = (const float4*)x;
        const int stride = gridDim.x * 512;
        for (int i = blockIdx.x * 512 + t; i < n4; i += stride) {
            float4 v = xv[i];
            m = fmaxf(m, fmaxf(fmaxf(fabsf(v.x), fabsf(v.y)), fmaxf(fabsf(v.z), fabsf(v.w))));
        }
        reduceAndAtomicMax(m, slots + 0);
    }
    gg.sync();
    phase_body<1>(x, b1, b2, b3, b4, wsf, slots, out, nTiles, waveId, totalWaves);
    gg.sync();
    phase_body<2>(x, b1, b2, b3, b4, wsf, slots, out, nTiles, waveId, totalWaves);
    gg.sync();
    phase_body<3>(x, b1, b2, b3, b4, wsf, slots, out, nTiles, waveId, totalWaves);
    gg.sync();
    phase_body<4>(x, b1, b2, b3, b4, wsf, slots, out, nTiles, waveId, totalWaves);
}

// ---- fallback staged path (r16, proven 163 us) ----
__global__ __launch_bounds__(1024, 4) void k_absmax(const float4* __restrict__ x,
                                                    unsigned int* __restrict__ slots, int n4) {
    float m = 0.f;
    for (int i = blockIdx.x * blockDim.x + threadIdx.x; i < n4; i += gridDim.x * blockDim.x) {
        float4 v = x[i];
        m = fmaxf(m, fmaxf(fmaxf(fabsf(v.x), fabsf(v.y)), fmaxf(fabsf(v.z), fabsf(v.w))));
    }
    reduceAndAtomicMax(m, slots + 0);
}

template <int STAGE, int WPB_, int TPW_>
DEV void stage_fixed(const float* x, const float* b1, const float* b2, const float* b3,
                     const float* b4, const float* wsf, unsigned int* slots, float* out) {
    const int waveId = blockIdx.x * WPB_ + (threadIdx.x >> 6);
    // fixed mapping: wave covers tiles [waveId*TPW_, (waveId+1)*TPW_) via stride trick
    // reuse grid-stride body with totalWaves = total tile groups
    // simplest: grid-stride with totalWaves = gridDim.x * WPB_ covers all tiles identically
    phase_body<STAGE>(x, b1, b2, b3, b4, wsf, slots, out, 65536, waveId, gridDim.x * WPB_);
}

__global__ __launch_bounds__(1024, 4) void k_s1(const float* x, const float* b1, const float* b2,
                                                const float* b3, const float* b4, const float* ws,
                                                unsigned int* slots, float* out) {
    stage_fixed<1, 16, 8>(x, b1, b2, b3, b4, ws, slots, out);
}
__global__ __launch_bounds__(1024, 4) void k_s2(const float* x, const float* b1, const float* b2,
                                                const float* b3, const float* b4, const float* ws,
                                                unsigned int* slots, float* out) {
    stage_fixed<2, 16, 8>(x, b1, b2, b3, b4, ws, slots, out);
}
__global__ __launch_bounds__(512, 2) void k_s3(const float* x, const float* b1, const float* b2,
                                               const float* b3, const float* b4, const float* ws,
                                               unsigned int* slots, float* out) {
    stage_fixed<3, 8, 16>(x, b1, b2, b3, b4, ws, slots, out);
}
__global__ __launch_bounds__(512, 2) void k_s4(const float* x, const float* b1, const float* b2,
                                               const float* b3, const float* b4, const float* ws,
                                               unsigned int* slots, float* out) {
    stage_fixed<4, 8, 16>(x, b1, b2, b3, b4, ws, slots, out);
}

extern "C" void kernel_launch(void* const* d_in, const int* in_sizes, int n_in,
                              void* d_out, int out_size, void* d_ws, size_t ws_size,
                              hipStream_t stream) {
    const float* x  = (const float*)d_in[0];
    const float* W1 = (const float*)d_in[1];
    const float* b1 = (const float*)d_in[2];
    const float* W2 = (const float*)d_in[3];
    const float* b2 = (const float*)d_in[4];
    const float* W3 = (const float*)d_in[5];
    const float* b3 = (const float*)d_in[6];
    const float* W4 = (const float*)d_in[7];
    const float* b4 = (const float*)d_in[8];
    float* out = (float*)d_out;
    float* ws = (float*)d_ws;
    unsigned int* slots = (unsigned int*)d_ws;

    const int B = in_sizes[0] / 16;   // 1 << 20 rows
    int nTiles = B / 16;              // 65536
    int n4 = in_sizes[0] / 4;

    k_quantw<<<1, 256, 0, stream>>>(W1, W2, W3, W4, ws);

    int dev = 0;
    (void)hipGetDevice(&dev);
    int nCU = 256;
    (void)hipDeviceGetAttribute(&nCU, hipDeviceAttributeMultiprocessorCount, dev);
    int bpc = 0;
    hipError_t qe = hipOccupancyMaxActiveBlocksPerMultiprocessor(&bpc, k_fused, 512, 0);
    bool tryCoop = (qe == hipSuccess && bpc >= 1);
    hipError_t e = hipErrorUnknown;
    if (tryCoop) {
        if (bpc > 2) bpc = 2;
        int gridB = nCU * bpc;
        if (gridB > 512) gridB = 512;
        const float* xp = x;
        void* args[] = {(void*)&xp, (void*)&b1, (void*)&b2, (void*)&b3, (void*)&b4,
                        (void*)&ws, (void*)&slots, (void*)&out, (void*)&nTiles, (void*)&n4};
        e = hipLaunchCooperativeKernel((void*)k_fused, dim3(gridB), dim3(512), args, 0, stream);
    }
    if (e != hipSuccess) {
        // fallback: r16 staged path
        k_absmax<<<512, 1024, 0, stream>>>((const float4*)x, slots, n4);
        k_s1<<<512, 1024, 0, stream>>>(x, b1, b2, b3, b4, ws, slots, out);
        k_s2<<<512, 1024, 0, stream>>>(x, b1, b2, b3, b4, ws, slots, out);
        k_s3<<<512, 512, 0, stream>>>(x, b1, b2, b3, b4, ws, slots, out);
        k_s4<<<512, 512, 0, stream>>>(x, b1, b2, b3, b4, ws, slots, out);
    }
}

// Round 18
// 160.668 us; speedup vs baseline: 1.0998x; 1.0998x over previous
//
#include <hip/hip_runtime.h>
#include <math.h>

#define DEV __device__ __forceinline__

typedef short s16x8 __attribute__((ext_vector_type(8)));
typedef float f32x4 __attribute__((ext_vector_type(4)));

// ---- ws dword layout ----
// [0..3]: reduction slots (bit patterns of non-negative floats)
static constexpr int W1S = 16;   // 64 per-out-row weight scales
static constexpr int W2S = 80;   // 32
static constexpr int W3S = 112;  // 32
static constexpr int W4S = 144;  // 5
static constexpr int F0  = 256;  // 18 A-fragments (weights), each 64 lanes x int4
// frag ids: 0..3 = A1[nt] | 4..11 = A2[mt*4+c] | 12..15 = A3[mt*2+c] | 16..17 = A4[c]

DEV float qbias(float b, float bs) {
    float q = rintf(b / bs);
    return fminf(fmaxf(q, -2.147483648e9f), 2.147483648e9f);
}

DEV unsigned short bf16b(float f) {  // values used are exact in bf16 -> truncate
    return (unsigned short)(__float_as_uint(f) >> 16);
}

DEV void reduceAndAtomicMax(float v, unsigned int* slot) {
    #pragma unroll
    for (int off = 32; off; off >>= 1) v = fmaxf(v, __shfl_xor(v, off));
    __shared__ float sm[16];
    const int wid = threadIdx.x >> 6;
    if ((threadIdx.x & 63) == 0) sm[wid] = v;
    __syncthreads();
    if (threadIdx.x == 0) {
        const int nw = blockDim.x >> 6;
        float m = sm[0];
        for (int i = 1; i < nw; i++) m = fmaxf(m, sm[i]);
        atomicMax(slot, __float_as_uint(m)); // non-negative: bit order == value order
    }
}

// ---- setup: quantize weights, emit k-permuted A-fragments (weights as MFMA A) ----
__global__ __launch_bounds__(256) void k_quantw(const float* __restrict__ W1,
                                                const float* __restrict__ W2,
                                                const float* __restrict__ W3,
                                                const float* __restrict__ W4,
                                                float* __restrict__ wsf) {
    __shared__ int wq1[64 * 16], wq2[32 * 64], wq3[32 * 32], wq4[5 * 32];
    int* wsi = (int*)wsf;
    const int t = threadIdx.x;
    if (t < 4) ((unsigned int*)wsf)[t] = 0u;

    const float* W = nullptr; int row = -1, cols = 0; int* dq = nullptr; float* dsc = nullptr;
    if (t < 64)       { W = W1; row = t;       cols = 16; dq = wq1 + row * 16; dsc = wsf + W1S + row; }
    else if (t < 96)  { W = W2; row = t - 64;  cols = 64; dq = wq2 + row * 64; dsc = wsf + W2S + row; }
    else if (t < 128) { W = W3; row = t - 96;  cols = 32; dq = wq3 + row * 32; dsc = wsf + W3S + row; }
    else if (t < 133) { W = W4; row = t - 128; cols = 32; dq = wq4 + row * 32; dsc = wsf + W4S + row; }
    if (row >= 0) {
        const float* src = W + row * cols;
        float m = 0.f;
        for (int i = 0; i < cols; i++) m = fmaxf(m, fabsf(src[i]));
        float s = fmaxf(m * (1.0f / 127.0f), 1e-8f);
        *dsc = s;
        for (int i = 0; i < cols; i++) {
            float q = fminf(fmaxf(rintf(src[i] / s), -128.f), 127.f);
            dq[i] = (int)q;
        }
    }
    __syncthreads();

    // A-fragment: lane l holds A[row = l&15][k = (l>>4)*8 + e].
    //  L1: k=8*grp+e -> feature (grp&1)*8 + e           (grp>>1 = hi/lo)
    //  L2/L3/L4 chunk c: k=8*grp+e -> feature 16c + 4*grp + (e&3)  (e>>2 = hi/lo)
    for (int sIdx = t; sIdx < 18 * 64; sIdx += 256) {
        const int f = sIdx >> 6, l = sIdx & 63;
        const int grp = l >> 4, li = l & 15;
        int dw[4];
        #pragma unroll
        for (int d = 0; d < 4; d++) {
            unsigned int hv[2];
            #pragma unroll
            for (int h = 0; h < 2; h++) {
                const int e = 2 * d + h;
                int wv;
                if (f < 4) {
                    wv = wq1[(f * 16 + li) * 16 + (grp & 1) * 8 + e];
                } else if (f < 12) {
                    int mt = (f - 4) >> 2, c = (f - 4) & 3;
                    wv = wq2[(mt * 16 + li) * 64 + 16 * c + 4 * grp + (e & 3)];
                } else if (f < 16) {
                    int mt = (f - 12) >> 1, c = (f - 12) & 1;
                    wv = wq3[(mt * 16 + li) * 32 + 16 * c + 4 * grp + (e & 3)];
                } else {
                    int c = f - 16;
                    wv = (li < 5) ? wq4[li * 32 + 16 * c + 4 * grp + (e & 3)] : 0;
                }
                hv[h] = bf16b((float)wv);
            }
            dw[d] = (int)(hv[0] | (hv[1] << 16));
        }
        ((int4*)(wsi + F0))[f * 64 + l] = make_int4(dw[0], dw[1], dw[2], dw[3]);
    }
}

// ---- K0: max|x| ----
__global__ __launch_bounds__(1024, 4) void k_absmax(const float4* __restrict__ x,
                                                    unsigned int* __restrict__ slots, int n4) {
    float m = 0.f;
    for (int i = blockIdx.x * blockDim.x + threadIdx.x; i < n4; i += gridDim.x * blockDim.x) {
        float4 v = x[i];
        m = fmaxf(m, fmaxf(fmaxf(fabsf(v.x), fabsf(v.y)), fmaxf(fabsf(v.z), fabsf(v.w))));
    }
    reduceAndAtomicMax(m, slots + 0);
}

// pack bf16 bits of two low16-zero floats into one dword: {b0>>16, b1>>16}
DEV int packhi(float q0, float q1) {
    return (int)__builtin_amdgcn_perm(__float_as_uint(q1), __float_as_uint(q0), 0x07060302u);
}

// quant(+relu) + truncation split; upper clamp provably never binds (r15-validated)
DEV void qsplit2(float a0, float a1, float2 c0, float2 c1, int& hw, int& lw) {
    float t0 = fmaf(a0, c0.x, c0.y);
    float t1 = fmaf(a1, c1.x, c1.y);
    float q0 = fmaxf(rintf(t0), 0.f);
    float q1 = fmaxf(rintf(t1), 0.f);
    float h0 = __uint_as_float(__float_as_uint(q0) & 0xFFFF0000u); // top 8 sig bits
    float h1 = __uint_as_float(__float_as_uint(q1) & 0xFFFF0000u);
    hw = packhi(h0, h1);
    lw = packhi(q0 - h0, q1 - h1);  // residual <= 7 sig bits, bf16-exact
}

DEV s16x8 mkfrag(f32x4 acc, const float2* cq) {
    int h01, h23, l01, l23;
    qsplit2(acc[0], acc[1], cq[0], cq[1], h01, l01);
    qsplit2(acc[2], acc[3], cq[2], cq[3], h23, l23);
    return __builtin_bit_cast(s16x8, make_int4(h01, h23, l01, l23));
}

// x-path: clamps provably never bind (r15-validated)
DEV float qxsel(float v, float inv0, bool hi) {
    float q = rintf(v * inv0);
    float h = __uint_as_float(__float_as_uint(q) & 0xFFFF0000u);
    return hi ? h : (q - h);
}

DEV s16x8 mkb1(float4 v0, float4 v1, float inv0, bool hi) {
    float p0 = qxsel(v0.x, inv0, hi), p1 = qxsel(v0.y, inv0, hi);
    float p2 = qxsel(v0.z, inv0, hi), p3 = qxsel(v0.w, inv0, hi);
    float p4 = qxsel(v1.x, inv0, hi), p5 = qxsel(v1.y, inv0, hi);
    float p6 = qxsel(v1.z, inv0, hi), p7 = qxsel(v1.w, inv0, hi);
    return __builtin_bit_cast(s16x8,
        make_int4(packhi(p0, p1), packhi(p2, p3), packhi(p4, p5), packhi(p6, p7)));
}

// ================= s1/s2: single-chain body (r16-proven) =================
template <int STAGE, int WPB_, int TPW_>
DEV void stage_body(const float* __restrict__ x,
                    const float* __restrict__ b1, const float* __restrict__ b2,
                    const float* __restrict__ wsf, unsigned int* __restrict__ slots) {
    __shared__ float2 QA[64], QB[32];
    const int t = threadIdx.x;
    const int w = t >> 6, l = t & 63;
    const int grp = l >> 4, li = l & 15;

    const float s0 = fmaxf(__uint_as_float(slots[0]) * (1.f / 32767.f), 1e-8f);
    float s1 = 1.f;
    if (STAGE >= 2) s1 = fmaxf(__uint_as_float(slots[1]) * (1.f / 32767.f), 1e-8f);
    const float inv0 = 1.f / s0;
    const float inv1 = (STAGE >= 2) ? 1.f / s1 : 0.f;

    if (t < 64) {
        float bs = wsf[W1S + t] * s0; float bi = qbias(b1[t], bs) * bs;
        QA[t] = (STAGE == 1) ? make_float2(bs, bi) : make_float2(bs * inv1, bi * inv1);
    }
    if (STAGE >= 2 && t >= 64 && t < 96) {
        int i = t - 64;
        float bs = wsf[W2S + i] * s1; float bi = qbias(b2[i], bs) * bs;
        QB[i] = make_float2(bs, bi);
    }
    __syncthreads();

    const int4* fr = (const int4*)((const int*)wsf + F0);
    s16x8 A1[4], A2[2][4];
    #pragma unroll
    for (int nt = 0; nt < 4; nt++) A1[nt] = __builtin_bit_cast(s16x8, fr[nt * 64 + l]);
    if (STAGE >= 2)
        #pragma unroll
        for (int mt = 0; mt < 2; mt++)
            #pragma unroll
            for (int c = 0; c < 4; c++) A2[mt][c] = __builtin_bit_cast(s16x8, fr[(4 + mt * 4 + c) * 64 + l]);

    float2 cq1[4][4];
    if (STAGE >= 2)
        #pragma unroll
        for (int nt = 0; nt < 4; nt++)
            #pragma unroll
            for (int r = 0; r < 4; r++) cq1[nt][r] = QA[16 * nt + 4 * grp + r];

    float ma1[4][4], ma2[2][4];
    if (STAGE == 1)
        #pragma unroll
        for (int nt = 0; nt < 4; nt++)
            #pragma unroll
            for (int r = 0; r < 4; r++) ma1[nt][r] = -3.402823466e38f;
    if (STAGE == 2)
        #pragma unroll
        for (int mt = 0; mt < 2; mt++)
            #pragma unroll
            for (int r = 0; r < 4; r++) ma2[mt][r] = -3.402823466e38f;

    const bool hiLane = (grp < 2);
    const size_t tile0 = ((size_t)blockIdx.x * WPB_ + w) * (size_t)TPW_;

    float4 px0, px1;
    {
        const float4* xr = (const float4*)(x + (tile0 * 16 + li) * 16 + (grp & 1) * 8);
        px0 = xr[0]; px1 = xr[1];
    }

    for (int it = 0; it < TPW_; ++it) {
        float4 v0 = px0, v1 = px1;
        if (it + 1 < TPW_) {
            const float4* xr = (const float4*)(x + ((tile0 + it + 1) * 16 + li) * 16 + (grp & 1) * 8);
            px0 = xr[0]; px1 = xr[1];
        }

        s16x8 b1v = mkb1(v0, v1, inv0, hiLane);

        s16x8 B2f[4];
        #pragma unroll
        for (int nt = 0; nt < 4; nt++) {
            f32x4 acc = {0.f, 0.f, 0.f, 0.f};
            acc = __builtin_amdgcn_mfma_f32_16x16x32_bf16(A1[nt], b1v, acc, 0, 0, 0);
            if constexpr (STAGE == 1) {
                #pragma unroll
                for (int r = 0; r < 4; r++) ma1[nt][r] = fmaxf(ma1[nt][r], acc[r]);
            } else {
                B2f[nt] = mkfrag(acc, cq1[nt]);
            }
        }
        if constexpr (STAGE == 1) continue;

        f32x4 acc2[2] = {{0.f, 0.f, 0.f, 0.f}, {0.f, 0.f, 0.f, 0.f}};
        #pragma unroll
        for (int c = 0; c < 4; c++) {
            acc2[0] = __builtin_amdgcn_mfma_f32_16x16x32_bf16(A2[0][c], B2f[c], acc2[0], 0, 0, 0);
            acc2[1] = __builtin_amdgcn_mfma_f32_16x16x32_bf16(A2[1][c], B2f[c], acc2[1], 0, 0, 0);
        }
        #pragma unroll
        for (int mt = 0; mt < 2; mt++)
            #pragma unroll
            for (int r = 0; r < 4; r++) ma2[mt][r] = fmaxf(ma2[mt][r], acc2[mt][r]);
    }

    if (STAGE == 1) {
        float vmax = 0.f;
        #pragma unroll
        for (int nt = 0; nt < 4; nt++)
            #pragma unroll
            for (int r = 0; r < 4; r++) {
                float2 c = QA[16 * nt + 4 * grp + r];
                vmax = fmaxf(vmax, fmaf(ma1[nt][r], c.x, c.y));
            }
        reduceAndAtomicMax(vmax, slots + 1);
    } else {
        float vmax = 0.f;
        #pragma unroll
        for (int mt = 0; mt < 2; mt++)
            #pragma unroll
            for (int r = 0; r < 4; r++) {
                float2 c = QB[16 * mt + 4 * grp + r];
                vmax = fmaxf(vmax, fmaf(ma2[mt][r], c.x, c.y));
            }
        reduceAndAtomicMax(vmax, slots + 2);
    }
}

// ================= s3/s4: 2-tile interleaved body (256-reg budget) =================
template <int STAGE, int WPB_, int TPW_>
DEV void stage_body2(const float* __restrict__ x,
                     const float* __restrict__ b1, const float* __restrict__ b2,
                     const float* __restrict__ b3, const float* __restrict__ b4,
                     const float* __restrict__ wsf, unsigned int* __restrict__ slots,
                     float* __restrict__ out) {
    __shared__ float2 QA[64], QB[32], QC[32], QD[16];
    const int t = threadIdx.x;
    const int w = t >> 6, l = t & 63;
    const int grp = l >> 4, li = l & 15;

    const float s0 = fmaxf(__uint_as_float(slots[0]) * (1.f / 32767.f), 1e-8f);
    const float s1 = fmaxf(__uint_as_float(slots[1]) * (1.f / 32767.f), 1e-8f);
    const float s2 = fmaxf(__uint_as_float(slots[2]) * (1.f / 32767.f), 1e-8f);
    float s3 = 1.f;
    if (STAGE >= 4) s3 = fmaxf(__uint_as_float(slots[3]) * (1.f / 32767.f), 1e-8f);
    const float inv0 = 1.f / s0, inv1 = 1.f / s1, inv2 = 1.f / s2;
    const float inv3 = (STAGE >= 4) ? 1.f / s3 : 0.f;

    if (t < 64) {
        float bs = wsf[W1S + t] * s0; float bi = qbias(b1[t], bs) * bs;
        QA[t] = make_float2(bs * inv1, bi * inv1);
    }
    if (t >= 64 && t < 96) {
        int i = t - 64;
        float bs = wsf[W2S + i] * s1; float bi = qbias(b2[i], bs) * bs;
        QB[i] = make_float2(bs * inv2, bi * inv2);
    }
    if (t >= 96 && t < 128) {
        int i = t - 96;
        float bs = wsf[W3S + i] * s2; float bi = qbias(b3[i], bs) * bs;
        QC[i] = (STAGE == 3) ? make_float2(bs, bi) : make_float2(bs * inv3, bi * inv3);
    }
    if (STAGE >= 4 && t >= 128 && t < 144) {
        int i = t - 128;
        if (i < 5) { float bs = wsf[W4S + i] * s3; QD[i] = make_float2(bs, qbias(b4[i], bs) * bs); }
        else QD[i] = make_float2(0.f, 0.f);
    }
    __syncthreads();

    const int4* fr = (const int4*)((const int*)wsf + F0);
    s16x8 A1[4], A2[2][4], A3[2][2], A4[2];
    #pragma unroll
    for (int nt = 0; nt < 4; nt++) A1[nt] = __builtin_bit_cast(s16x8, fr[nt * 64 + l]);
    #pragma unroll
    for (int mt = 0; mt < 2; mt++)
        #pragma unroll
        for (int c = 0; c < 4; c++) A2[mt][c] = __builtin_bit_cast(s16x8, fr[(4 + mt * 4 + c) * 64 + l]);
    #pragma unroll
    for (int mt = 0; mt < 2; mt++)
        #pragma unroll
        for (int c = 0; c < 2; c++) A3[mt][c] = __builtin_bit_cast(s16x8, fr[(12 + mt * 2 + c) * 64 + l]);
    if (STAGE >= 4) {
        A4[0] = __builtin_bit_cast(s16x8, fr[16 * 64 + l]);
        A4[1] = __builtin_bit_cast(s16x8, fr[17 * 64 + l]);
    }

    float2 cq1[4][4], cq2[2][4], cq3[2][4], e4[4];
    #pragma unroll
    for (int nt = 0; nt < 4; nt++)
        #pragma unroll
        for (int r = 0; r < 4; r++) cq1[nt][r] = QA[16 * nt + 4 * grp + r];
    #pragma unroll
    for (int mt = 0; mt < 2; mt++)
        #pragma unroll
        for (int r = 0; r < 4; r++) cq2[mt][r] = QB[16 * mt + 4 * grp + r];
    if (STAGE >= 4) {
        #pragma unroll
        for (int mt = 0; mt < 2; mt++)
            #pragma unroll
            for (int r = 0; r < 4; r++) cq3[mt][r] = QC[16 * mt + 4 * grp + r];
        #pragma unroll
        for (int r = 0; r < 4; r++) e4[r] = QD[4 * grp + r];
    }

    float ma3[2][4];
    if (STAGE == 3)
        #pragma unroll
        for (int mt = 0; mt < 2; mt++)
            #pragma unroll
            for (int r = 0; r < 4; r++) ma3[mt][r] = -3.402823466e38f;

    const bool hiLane = (grp < 2);
    const size_t tile0 = ((size_t)blockIdx.x * WPB_ + w) * (size_t)TPW_;

    float4 pa0, pa1, pb0, pb1;
    {
        const float4* xa = (const float4*)(x + (tile0 * 16 + li) * 16 + (grp & 1) * 8);
        pa0 = xa[0]; pa1 = xa[1];
        const float4* xb = (const float4*)(x + ((tile0 + 1) * 16 + li) * 16 + (grp & 1) * 8);
        pb0 = xb[0]; pb1 = xb[1];
    }

    for (int it = 0; it < TPW_; it += 2) {
        float4 va0 = pa0, va1 = pa1, vb0 = pb0, vb1 = pb1;
        if (it + 2 < TPW_) {
            const float4* xa = (const float4*)(x + ((tile0 + it + 2) * 16 + li) * 16 + (grp & 1) * 8);
            pa0 = xa[0]; pa1 = xa[1];
            const float4* xb = (const float4*)(x + ((tile0 + it + 3) * 16 + li) * 16 + (grp & 1) * 8);
            pb0 = xb[0]; pb1 = xb[1];
        }
        const size_t rowA = (tile0 + it) * 16, rowB = (tile0 + it + 1) * 16;

        s16x8 b1a = mkb1(va0, va1, inv0, hiLane);
        s16x8 b1b = mkb1(vb0, vb1, inv0, hiLane);

        // L1 (8 independent MFMAs across the two chains)
        s16x8 B2a[4], B2b[4];
        #pragma unroll
        for (int nt = 0; nt < 4; nt++) {
            f32x4 aa = {0.f, 0.f, 0.f, 0.f}, ab = {0.f, 0.f, 0.f, 0.f};
            aa = __builtin_amdgcn_mfma_f32_16x16x32_bf16(A1[nt], b1a, aa, 0, 0, 0);
            ab = __builtin_amdgcn_mfma_f32_16x16x32_bf16(A1[nt], b1b, ab, 0, 0, 0);
            B2a[nt] = mkfrag(aa, cq1[nt]);
            B2b[nt] = mkfrag(ab, cq1[nt]);
        }

        // L2
        f32x4 a2a[2] = {{0.f, 0.f, 0.f, 0.f}, {0.f, 0.f, 0.f, 0.f}};
        f32x4 a2b[2] = {{0.f, 0.f, 0.f, 0.f}, {0.f, 0.f, 0.f, 0.f}};
        #pragma unroll
        for (int c = 0; c < 4; c++) {
            a2a[0] = __builtin_amdgcn_mfma_f32_16x16x32_bf16(A2[0][c], B2a[c], a2a[0], 0, 0, 0);
            a2b[0] = __builtin_amdgcn_mfma_f32_16x16x32_bf16(A2[0][c], B2b[c], a2b[0], 0, 0, 0);
            a2a[1] = __builtin_amdgcn_mfma_f32_16x16x32_bf16(A2[1][c], B2a[c], a2a[1], 0, 0, 0);
            a2b[1] = __builtin_amdgcn_mfma_f32_16x16x32_bf16(A2[1][c], B2b[c], a2b[1], 0, 0, 0);
        }

        s16x8 B3a[2], B3b[2];
        #pragma unroll
        for (int c = 0; c < 2; c++) {
            B3a[c] = mkfrag(a2a[c], cq2[c]);
            B3b[c] = mkfrag(a2b[c], cq2[c]);
        }

        // L3
        f32x4 a3a[2] = {{0.f, 0.f, 0.f, 0.f}, {0.f, 0.f, 0.f, 0.f}};
        f32x4 a3b[2] = {{0.f, 0.f, 0.f, 0.f}, {0.f, 0.f, 0.f, 0.f}};
        #pragma unroll
        for (int c = 0; c < 2; c++) {
            a3a[0] = __builtin_amdgcn_mfma_f32_16x16x32_bf16(A3[0][c], B3a[c], a3a[0], 0, 0, 0);
            a3b[0] = __builtin_amdgcn_mfma_f32_16x16x32_bf16(A3[0][c], B3b[c], a3b[0], 0, 0, 0);
            a3a[1] = __builtin_amdgcn_mfma_f32_16x16x32_bf16(A3[1][c], B3a[c], a3a[1], 0, 0, 0);
            a3b[1] = __builtin_amdgcn_mfma_f32_16x16x32_bf16(A3[1][c], B3b[c], a3b[1], 0, 0, 0);
        }
        if constexpr (STAGE == 3) {
            #pragma unroll
            for (int mt = 0; mt < 2; mt++)
                #pragma unroll
                for (int r = 0; r < 4; r++)
                    ma3[mt][r] = fmaxf(ma3[mt][r], fmaxf(a3a[mt][r], a3b[mt][r]));
            continue;
        }

        if constexpr (STAGE == 4) {
            s16x8 B4a[2], B4b[2];
            #pragma unroll
            for (int c = 0; c < 2; c++) {
                B4a[c] = mkfrag(a3a[c], cq3[c]);
                B4b[c] = mkfrag(a3b[c], cq3[c]);
            }

            f32x4 a4a = {0.f, 0.f, 0.f, 0.f}, a4b = {0.f, 0.f, 0.f, 0.f};
            a4a = __builtin_amdgcn_mfma_f32_16x16x32_bf16(A4[0], B4a[0], a4a, 0, 0, 0);
            a4b = __builtin_amdgcn_mfma_f32_16x16x32_bf16(A4[0], B4b[0], a4b, 0, 0, 0);
            a4a = __builtin_amdgcn_mfma_f32_16x16x32_bf16(A4[1], B4a[1], a4a, 0, 0, 0);
            a4b = __builtin_amdgcn_mfma_f32_16x16x32_bf16(A4[1], B4b[1], a4b, 0, 0, 0);

            float lgA0 = fmaf(a4a[0], e4[0].x, e4[0].y), lgB0 = fmaf(a4b[0], e4[0].x, e4[0].y);
            float lgA1 = fmaf(a4a[1], e4[1].x, e4[1].y), lgB1 = fmaf(a4b[1], e4[1].x, e4[1].y);
            float lgA2 = fmaf(a4a[2], e4[2].x, e4[2].y), lgB2 = fmaf(a4b[2], e4[2].x, e4[2].y);
            float lgA3 = fmaf(a4a[3], e4[3].x, e4[3].y), lgB3 = fmaf(a4b[3], e4[3].x, e4[3].y);
            float lgA4 = __shfl(lgA0, li + 16);
            float lgB4 = __shfl(lgB0, li + 16);

            if (l < 16) {
                {
                    float m = fmaxf(fmaxf(fmaxf(lgA0, lgA1), fmaxf(lgA2, lgA3)), lgA4);
                    float e0 = __expf(lgA0 - m), e1 = __expf(lgA1 - m), e2 = __expf(lgA2 - m),
                          e3 = __expf(lgA3 - m), ee = __expf(lgA4 - m);
                    float r = 1.f / (e0 + e1 + e2 + e3 + ee);
                    float* dst = out + (rowA + l) * 5;
                    dst[0] = e0 * r; dst[1] = e1 * r; dst[2] = e2 * r; dst[3] = e3 * r; dst[4] = ee * r;
                }
                {
                    float m = fmaxf(fmaxf(fmaxf(lgB0, lgB1), fmaxf(lgB2, lgB3)), lgB4);
                    float e0 = __expf(lgB0 - m), e1 = __expf(lgB1 - m), e2 = __expf(lgB2 - m),
                          e3 = __expf(lgB3 - m), ee = __expf(lgB4 - m);
                    float r = 1.f / (e0 + e1 + e2 + e3 + ee);
                    float* dst = out + (rowB + l) * 5;
                    dst[0] = e0 * r; dst[1] = e1 * r; dst[2] = e2 * r; dst[3] = e3 * r; dst[4] = ee * r;
                }
            }
        }
    }

    if (STAGE == 3) {
        float vmax = 0.f;
        #pragma unroll
        for (int mt = 0; mt < 2; mt++)
            #pragma unroll
            for (int r = 0; r < 4; r++) {
                float2 c = QC[16 * mt + 4 * grp + r];
                vmax = fmaxf(vmax, fmaf(ma3[mt][r], c.x, c.y));
            }
        reduceAndAtomicMax(vmax, slots + 3);
    }
}

// s1-s2: 1024-thread blocks (r16-proven)
__global__ __launch_bounds__(1024, 4) void k_s1(const float* x, const float* b1, const float* b2,
                                                const float* ws, unsigned int* slots) {
    stage_body<1, 16, 8>(x, b1, b2, ws, slots);
}
__global__ __launch_bounds__(1024, 4) void k_s2(const float* x, const float* b1, const float* b2,
                                                const float* ws, unsigned int* slots) {
    stage_body<2, 16, 8>(x, b1, b2, ws, slots);
}
// s3, s4: 512-thread blocks, 256-reg budget, 2-tile interleaved chains
__global__ __launch_bounds__(512, 2) void k_s3(const float* x, const float* b1, const float* b2,
                                               const float* b3, const float* b4, const float* ws,
                                               unsigned int* slots, float* out) {
    stage_body2<3, 8, 16>(x, b1, b2, b3, b4, ws, slots, out);
}
__global__ __launch_bounds__(512, 2) void k_s4(const float* x, const float* b1, const float* b2,
                                               const float* b3, const float* b4, const float* ws,
                                               unsigned int* slots, float* out) {
    stage_body2<4, 8, 16>(x, b1, b2, b3, b4, ws, slots, out);
}

extern "C" void kernel_launch(void* const* d_in, const int* in_sizes, int n_in,
                              void* d_out, int out_size, void* d_ws, size_t ws_size,
                              hipStream_t stream) {
    const float* x  = (const float*)d_in[0];
    const float* W1 = (const float*)d_in[1];
    const float* b1 = (const float*)d_in[2];
    const float* W2 = (const float*)d_in[3];
    const float* b2 = (const float*)d_in[4];
    const float* W3 = (const float*)d_in[5];
    const float* b3 = (const float*)d_in[6];
    const float* W4 = (const float*)d_in[7];
    const float* b4 = (const float*)d_in[8];
    float* out = (float*)d_out;
    float* ws = (float*)d_ws;
    unsigned int* slots = (unsigned int*)d_ws;

    const int B = in_sizes[0] / 16;                       // 1 << 20 rows
    const int blocks12 = B / (16 * 8 * 16);               // 512
    const int blocks34 = B / (8 * 16 * 16);               // 512

    k_quantw<<<1, 256, 0, stream>>>(W1, W2, W3, W4, ws);
    k_absmax<<<512, 1024, 0, stream>>>((const float4*)x, slots, in_sizes[0] / 4);
    k_s1<<<blocks12, 1024, 0, stream>>>(x, b1, b2, ws, slots);
    k_s2<<<blocks12, 1024, 0, stream>>>(x, b1, b2, ws, slots);
    k_s3<<<blocks34, 512, 0, stream>>>(x, b1, b2, b3, b4, ws, slots, out);
    k_s4<<<blocks34, 512, 0, stream>>>(x, b1, b2, b3, b4, ws, slots, out);
}